// Round 9
// baseline (352.367 us; speedup 1.0000x reference)
//
#include <hip/hip_runtime.h>

#define BATCH   128
#define NUM_IN  4096
#define LVL     8
#define HID     32768
#define KH      32
#define OUTN    256
#define KOUT    64
#define SCALEA  4.9f

// Input u8 affine quantization range [-QR, QR]
#define QR      6.0f
#define QSTEP   (2.0f * QR / 255.0f)   // dequant scale
#define INV255  (1.0f / 255.0f)

#define NODES   266240              // NUM_IN + LVL*HID

// Round-8 post-mortem: sliced levels were L2-resident (FETCH 17 MB) but SLOWER
// than the L3 path -- the grouped/vector inner loop (LDS tile, cndmask dequant,
// ushort unpack, multi-segment TA scatter) costs ~26-38 cy/gather-instr vs the
// scalar-path kernels' ~5-8 (level0 pulls ~30 TB/s from L2 with the same 1.05M
// instruction count).  This round keeps slicing but with the LEAN loop:
//   wave = one (h, slice); j,wk wave-uniform scalars (s_load + SALU dequant);
//   lane = batch element; 1-byte loads (v_cvt_f32_ubyte0 + v_fmac = 2 VALU/k);
//   address = SGPR base + lane -> single contiguous segment.
// Placement (per-XCD footprint must fit 4 MiB L2):
//   L1: S=2, 64-B byte records, 64 lanes        (36864*64B  = 2.25 MB) lean_s2
//   L2: S=4, 32-B byte records, 32 active lanes (69632*32B  = 2.23 MB) lean_s4
//   L3: S=4                                      (102400*32B = 3.28 MB) lean_s4
//   L4..L7: proven deep128 L3-path, 36us/level (byte-bound)
// Byte tables: s2b[2][36864][64], s4b[4][102400][32]; ext128's pair layout is
// byte-compatible (byte index == batch element).
#define S2_NODES 36864
#define S4_NODES 102400
#define S2_SLICE_B (S2_NODES * 64u)   // bytes per s2b slice
#define S4_SLICE_B (S4_NODES * 32u)   // bytes per s4b slice

__device__ __forceinline__ unsigned short f2bf(float f) {
    unsigned u = __float_as_uint(f);
    u += 0x7FFFu + ((u >> 16) & 1u);   // round-to-nearest-even
    return (unsigned short)(u >> 16);
}
__device__ __forceinline__ float bf_lo(unsigned u) { return __uint_as_float(u << 16); }
__device__ __forceinline__ float bf_hi(unsigned u) { return __uint_as_float(u & 0xFFFF0000u); }

__device__ __forceinline__ unsigned q_in(float x) {   // input -> u8, range [-QR, QR]
    float t = (x + QR) * (255.0f / (2.0f * QR));
    t = fminf(fmaxf(t, 0.f), 255.f);
    return __float2uint_rn(t);
}

// ---------------------------------------------------------------------------
// Transpose x [B, NUM_IN] f32 -> in_bf (bf16 pairs, for level0) + input region
// of ext128, s2b, s4b.
// ---------------------------------------------------------------------------
__global__ __launch_bounds__(256) void transpose_x(const float* __restrict__ x,
                                                   unsigned* __restrict__ in_bf,
                                                   unsigned short* __restrict__ ext128,
                                                   unsigned short* __restrict__ s2b,
                                                   unsigned short* __restrict__ s4b) {
    __shared__ float lds[64][129];
    const int n0 = blockIdx.x * 64;
    const int t  = threadIdx.x;
    #pragma unroll
    for (int it = 0; it < 32; ++it) {
        int i = it * 256 + t;
        int b = i >> 6;
        int n = i & 63;
        lds[n][b] = x[b * NUM_IN + n0 + n];
    }
    __syncthreads();
    #pragma unroll
    for (int it = 0; it < 16; ++it) {
        int i  = it * 256 + t;      // 64 nodes x 64 batch-pairs
        int n  = i >> 6;
        int bp = i & 63;            // pair index: bytes/batch 2bp, 2bp+1
        float v0 = lds[n][2 * bp], v1 = lds[n][2 * bp + 1];
        in_bf[(n0 + n) * 64 + bp] = (unsigned)f2bf(v0) | ((unsigned)f2bf(v1) << 16);
        unsigned short q = (unsigned short)(q_in(v0) | (q_in(v1) << 8));
        unsigned node = (unsigned)(n0 + n);
        ext128[node * 64u + (unsigned)bp] = q;
        // s2b ushort view: slice = bp>>5, ushort off = node*32 + (bp&31)
        s2b[(unsigned)(bp >> 5) * (S2_SLICE_B / 2) + node * 32u + (unsigned)(bp & 31)] = q;
        // s4b ushort view: slice = bp>>4, ushort off = node*16 + (bp&15)
        s4b[(unsigned)(bp >> 4) * (S4_SLICE_B / 2) + node * 16u + (unsigned)(bp & 15)] = q;
    }
}

// ---------------------------------------------------------------------------
// Level 0: all sources are inputs. bf16 gathers from the 1 MB L2-resident
// in_bf table; writes ext128 + s2b + s4b.
// ---------------------------------------------------------------------------
__global__ __launch_bounds__(256) void level0(const unsigned* __restrict__ in_bf,
                                              unsigned short* __restrict__ ext128,
                                              unsigned short* __restrict__ s2b,
                                              unsigned short* __restrict__ s4b,
                                              const int* __restrict__ idx,
                                              const float* __restrict__ w) {
    const int lane = threadIdx.x & 63;
    int h = (blockIdx.x << 2) + (threadIdx.x >> 6);
    h = __builtin_amdgcn_readfirstlane(h);
    const int*   ip = idx + h * KH;
    const float* wp = w   + h * KH;
    float ax = 0.f, ay = 0.f;
    #pragma unroll
    for (int k = 0; k < KH; ++k) {
        int   j  = __builtin_amdgcn_readfirstlane(ip[k]);
        float wk = wp[k];
        unsigned v = in_bf[(unsigned)j * 64 + lane];
        ax = fmaf(wk, bf_lo(v), ax);
        ay = fmaf(wk, bf_hi(v), ay);
    }
    unsigned qx = __float2uint_rn(255.f / (1.f + __expf(-SCALEA * ax)));
    unsigned qy = __float2uint_rn(255.f / (1.f + __expf(-SCALEA * ay)));
    unsigned short q = (unsigned short)(qx | (qy << 8));
    unsigned node = (unsigned)(NUM_IN + h);
    ext128[node * 64u + (unsigned)lane] = q;
    s2b[(unsigned)(lane >> 5) * (S2_SLICE_B / 2) + node * 32u + (unsigned)(lane & 31)] = q;
    s4b[(unsigned)(lane >> 4) * (S4_SLICE_B / 2) + node * 16u + (unsigned)(lane & 15)] = q;
}

// ---------------------------------------------------------------------------
// Level 1: LEAN S=2 path.  Wave = one (h, slice); slice = bid&1 (XCD parity
// under round-robin); lane = batch element s*64+lane; scalar j/wk; 1-byte
// contiguous 64-B gather per (h,k).  Writes ext128 bytes + s4b bytes.
// ---------------------------------------------------------------------------
__global__ __launch_bounds__(256) void lean_s2(const unsigned char* __restrict__ s2b,
                                               unsigned char* __restrict__ ext128b,
                                               unsigned char* __restrict__ s4b,
                                               const int* __restrict__ idx,
                                               const float* __restrict__ w,
                                               int nbase) {  // 36864
    const int lane = threadIdx.x & 63;
    const int bid  = blockIdx.x;
    const int s    = bid & 1;
    int h = (bid >> 1) * 4 + (threadIdx.x >> 6);
    h = __builtin_amdgcn_readfirstlane(h);
    const int*   ip = idx + h * KH;
    const float* wp = w   + h * KH;
    const unsigned char* base = s2b + (unsigned)s * S2_SLICE_B + (unsigned)lane;

    float ax = 0.f, bias = 0.f;
    #pragma unroll
    for (int k = 0; k < KH; ++k) {
        int   j  = __builtin_amdgcn_readfirstlane(ip[k]);
        float wk = wp[k];
        bool isin = (j < NUM_IN);
        float a = wk * (isin ? QSTEP : INV255);    // scalar
        bias   += isin ? (-QR * wk) : 0.f;         // scalar
        float v = (float)base[(unsigned)j * 64u];  // ubyte -> cvt
        ax = fmaf(a, v, ax);
    }
    ax += bias;

    unsigned qv = __float2uint_rn(255.f / (1.f + __expf(-SCALEA * ax)));
    unsigned node = (unsigned)(nbase + h);
    unsigned b    = (unsigned)(s * 64 + lane);     // batch element
    ext128b[node * 128u + b] = (unsigned char)qv;
    s4b[(b >> 5) * S4_SLICE_B + node * 32u + (b & 31)] = (unsigned char)qv;
}

// ---------------------------------------------------------------------------
// Levels 2,3: LEAN S=4 path.  Wave = one (h, slice); slice = bid&3; lanes
// 0..31 = batch elements s*32+lane; scalar j/wk; 1-byte contiguous 32-B
// gather per (h,k).  write_s4 only at level 2.
// ---------------------------------------------------------------------------
__global__ __launch_bounds__(256) void lean_s4(const unsigned char* __restrict__ s4in,
                                               unsigned char* __restrict__ ext128b,
                                               unsigned char* __restrict__ s4out,
                                               const int* __restrict__ idx,
                                               const float* __restrict__ w,
                                               int nbase,      // 69632 / 102400
                                               int write_s4) {
    const int lane = threadIdx.x & 63;
    const int bid  = blockIdx.x;
    const int s    = bid & 3;
    int h = (bid >> 2) * 4 + (threadIdx.x >> 6);
    h = __builtin_amdgcn_readfirstlane(h);

    if (lane < 32) {
        const int*   ip = idx + h * KH;
        const float* wp = w   + h * KH;
        const unsigned char* base = s4in + (unsigned)s * S4_SLICE_B + (unsigned)lane;

        float ax = 0.f, bias = 0.f;
        #pragma unroll
        for (int k = 0; k < KH; ++k) {
            int   j  = __builtin_amdgcn_readfirstlane(ip[k]);
            float wk = wp[k];
            bool isin = (j < NUM_IN);
            float a = wk * (isin ? QSTEP : INV255);
            bias   += isin ? (-QR * wk) : 0.f;
            float v = (float)base[(unsigned)j * 32u];
            ax = fmaf(a, v, ax);
        }
        ax += bias;

        unsigned qv = __float2uint_rn(255.f / (1.f + __expf(-SCALEA * ax)));
        unsigned node = (unsigned)(nbase + h);
        ext128b[node * 128u + (unsigned)(s * 32 + lane)] = (unsigned char)qv;
        if (write_s4)
            s4out[(unsigned)s * S4_SLICE_B + node * 32u + (unsigned)lane] = (unsigned char)qv;
    }
}

// ---------------------------------------------------------------------------
// Levels 4..7: proven baseline L3-path.  Wave = one h, 64 lanes full batch,
// one 128-B gather per (h,k).  ~36us/level, L3-byte-bound.
// ---------------------------------------------------------------------------
__global__ __launch_bounds__(256) void deep128(unsigned short* __restrict__ ext128,
                                               const int* __restrict__ idx,
                                               const float* __restrict__ w,
                                               int nbase) {  // NUM_IN + l*HID
    const int lane = threadIdx.x & 63;
    int h = (blockIdx.x << 2) + (threadIdx.x >> 6);
    h = __builtin_amdgcn_readfirstlane(h);
    const int*   ip = idx + h * KH;
    const float* wp = w   + h * KH;

    float ax = 0.f, ay = 0.f, bias = 0.f;
    #pragma unroll
    for (int k = 0; k < KH; ++k) {
        int   j  = __builtin_amdgcn_readfirstlane(ip[k]);
        float wk = wp[k];
        bool isin = (j < NUM_IN);
        float a = wk * (isin ? QSTEP : INV255);
        bias   += isin ? (-QR * wk) : 0.f;
        unsigned tt = ext128[(unsigned)j * 64u + (unsigned)lane];
        ax = fmaf(a, (float)(tt & 0xFFu), ax);
        ay = fmaf(a, (float)(tt >> 8),   ay);
    }
    ax += bias;
    ay += bias;

    unsigned qx = __float2uint_rn(255.f / (1.f + __expf(-SCALEA * ax)));
    unsigned qy = __float2uint_rn(255.f / (1.f + __expf(-SCALEA * ay)));
    ext128[(unsigned)(nbase + h) * 64u + (unsigned)lane] =
        (unsigned short)(qx | (qy << 8));
}

// ---------------------------------------------------------------------------
// Output layer: tiny (O=256); baseline structure on ext128.
// ---------------------------------------------------------------------------
__global__ __launch_bounds__(256) void output_layer(const unsigned short* __restrict__ ext128,
                                                    const int* __restrict__ idx,
                                                    const float* __restrict__ w,
                                                    float* __restrict__ out) {
    const int lane = threadIdx.x & 63;
    int o = (blockIdx.x << 2) + (threadIdx.x >> 6);
    o = __builtin_amdgcn_readfirstlane(o);
    const int*   ip = idx + o * KOUT;
    const float* wp = w   + o * KOUT;

    float ax = 0.f, ay = 0.f, bias = 0.f;
    #pragma unroll
    for (int k = 0; k < KOUT; ++k) {
        int   j  = __builtin_amdgcn_readfirstlane(ip[k]);
        float wk = wp[k];
        bool isin = (j < NUM_IN);
        float a = wk * (isin ? QSTEP : INV255);
        bias   += isin ? (-QR * wk) : 0.f;
        unsigned tt = ext128[(unsigned)j * 64u + (unsigned)lane];
        ax = fmaf(a, (float)(tt & 0xFFu), ax);
        ay = fmaf(a, (float)(tt >> 8),   ay);
    }
    ax += bias;
    ay += bias;
    out[(2 * lane + 0) * OUTN + o] = 1.f / (1.f + __expf(-SCALEA * ax));
    out[(2 * lane + 1) * OUTN + o] = 1.f / (1.f + __expf(-SCALEA * ay));
}

extern "C" void kernel_launch(void* const* d_in, const int* in_sizes, int n_in,
                              void* d_out, int out_size, void* d_ws, size_t ws_size,
                              hipStream_t stream) {
    // setup_inputs() order: x, w_hidden, w_out, idx_hidden, idx_out
    const float* x          = (const float*)d_in[0];
    const float* w_hidden   = (const float*)d_in[1];
    const float* w_out      = (const float*)d_in[2];
    const int*   idx_hidden = (const int*)  d_in[3];
    const int*   idx_out    = (const int*)  d_in[4];
    float* out = (float*)d_out;

    char* ws = (char*)d_ws;
    unsigned*       in_bf  = (unsigned*)      (ws + 0);           //  1,048,576 B
    unsigned short* ext128 = (unsigned short*)(ws + 1048576);     // 34,078,720 B
    unsigned short* s2b    = (unsigned short*)(ws + 35127296);    //  4,718,592 B
    unsigned short* s4b    = (unsigned short*)(ws + 39845888);    // 13,107,200 B

    transpose_x<<<NUM_IN / 64, 256, 0, stream>>>(x, in_bf, ext128, s2b, s4b);

    level0<<<HID / 4, 256, 0, stream>>>(in_bf, ext128, s2b, s4b, idx_hidden, w_hidden);

    // Level 1: lean S=2 (reads s2b bytes, writes ext128 + s4b bytes)
    lean_s2<<<(HID / 4) * 2, 256, 0, stream>>>(
        (const unsigned char*)s2b, (unsigned char*)ext128, (unsigned char*)s4b,
        idx_hidden + (size_t)1 * HID * KH,
        w_hidden   + (size_t)1 * HID * KH,
        NUM_IN + 1 * HID);

    // Levels 2,3: lean S=4 (read s4b; level 2 also writes s4b)
    for (int l = 2; l <= 3; ++l) {
        lean_s4<<<(HID / 4) * 4, 256, 0, stream>>>(
            (const unsigned char*)s4b, (unsigned char*)ext128, (unsigned char*)s4b,
            idx_hidden + (size_t)l * HID * KH,
            w_hidden   + (size_t)l * HID * KH,
            NUM_IN + l * HID,
            (l == 2) ? 1 : 0);
    }

    // Levels 4..7: baseline L3-path
    for (int l = 4; l < LVL; ++l) {
        deep128<<<HID / 4, 256, 0, stream>>>(
            ext128,
            idx_hidden + (size_t)l * HID * KH,
            w_hidden   + (size_t)l * HID * KH,
            NUM_IN + l * HID);
    }

    output_layer<<<OUTN / 4, 256, 0, stream>>>(ext128, idx_out, w_out, out);
}